// Round 14
// baseline (1013.467 us; speedup 1.0000x reference)
//
#include <hip/hip_runtime.h>
#include <stdint.h>

#define Tsz 512
#define Dsz 256

// prog[] role indices
#define R_VAN 0
#define R_L1U(w) (1 + (w))
#define R_L2U(w) (5 + (w))
#define R_GX  9
#define R_GR0 10
#define R_GR1 11

union UHp { uint32_t u; _Float16 s[2]; };
__device__ __forceinline__ uint32_t packh(float a, float b) {
    UHp x; x.s[0] = (_Float16)a; x.s[1] = (_Float16)b; return x.u;
}
__device__ __forceinline__ float dot2(uint32_t w, uint32_t a, float c) {
#if __has_builtin(__builtin_amdgcn_fdot2)
    typedef _Float16 h2 __attribute__((ext_vector_type(2)));
    union U { uint32_t u; h2 h; };
    U W, A; W.u = w; A.u = a;
    return __builtin_amdgcn_fdot2(W.h, A.h, c, false);
#else
    float d;
    asm("v_dot2_f32_f16 %0, %1, %2, %3" : "=v"(d) : "v"(w), "v"(a), "v"(c));
    return d;
#endif
}
__device__ __forceinline__ float fsig(float x)  { return 1.0f / (1.0f + __expf(-x)); }
__device__ __forceinline__ float ftanh(float x) { return 2.0f / (1.0f + __expf(-2.0f * x)) - 1.0f; }

#define D4(ACC, WP, V) \
    do { ACC = dot2((WP)[0], (V).x, ACC); ACC = dot2((WP)[1], (V).y, ACC); \
         ACC = dot2((WP)[2], (V).z, ACC); ACC = dot2((WP)[3], (V).w, ACC); } while (0)
#define D4X(A, X, WP, V) \
    do { A = dot2((WP)[0], (V).x, A); X = dot2((WP)[1], (V).y, X); \
         A = dot2((WP)[2], (V).z, A); X = dot2((WP)[3], (V).w, X); } while (0)

// cached flag wait (monotonic counters)
#define WAITGE(cache, ridx, need) \
    do { if ((cache) < (need)) { \
        volatile const int* _pf = (volatile const int*)&prog[(ridx)]; \
        int _v = *_pf; \
        while (_v < (need)) _v = *_pf; \
        (cache) = _v; } } while (0)

#define SIGNAL(ridx, val) \
    do { asm volatile("s_waitcnt lgkmcnt(0)" ::: "memory"); \
         if (lane == 0) *((volatile int*)&prog[(ridx)]) = (val); } while (0)

// Block = 2 batch rows, 768 threads = 12 waves (3/SIMD), grid 256 (1 blk/CU).
// Elastic flag pipeline (r10-validated). KEY CHANGES vs r10 champion:
//  (1) per-branch-scoped weight arrays -> max live frame ~126 regs (r10's
//      unified wreg[128] forced a ~170-reg frame against a 112 grant ->
//      AGPR-copy tax on L2/GX/GR weight accesses every iteration);
//  (2) waves_per_eu(3,3) matches geometry -> budget 512/3 ~ 170/wave;
//  (3) L1/L2 split 4 ways (1 col/lane, quad-gate shfl combine, r7/r11-
//      validated numerics) so no role needs >96 weight regs;
//  (4) 3 waves/SIMD for latency hiding at ~same instruction count.
// Roles by wv: 0-3 L2u0-3 | 4-7 L1u0-3 | 8 GR0 | 9 GR1 | 10 VAN | 11 GX
// SIMD (wv&3): S0{L2u0,L1u0,GR0} S1{L2u1,L1u1,GR1} S2{L2u2,L1u2,VAN}
//              S3{L2u3,L1u3,GX}
__global__ __attribute__((amdgpu_flat_work_group_size(768, 768),
                          amdgpu_waves_per_eu(3, 3)))
void rnn12e(
    const float* __restrict__ pix,
    const float* __restrict__ van_wi, const float* __restrict__ van_bi,
    const float* __restrict__ van_wh, const float* __restrict__ van_bh,
    const float* __restrict__ w1g, const float* __restrict__ b1g,
    const float* __restrict__ w2g, const float* __restrict__ b2g,
    const float* __restrict__ gwi, const float* __restrict__ gwh,
    const float* __restrict__ gb,
    const float* __restrict__ mw1, const float* __restrict__ mb1,
    const float* __restrict__ mw2, const float* __restrict__ mb2,
    const float* __restrict__ mw3, const float* __restrict__ mb3,
    const float* __restrict__ sf,
    float* __restrict__ out)
{
    const int tid  = threadIdx.x;
    const int wv   = tid >> 6;
    const int lane = tid & 63;
    const int r0   = 2 * blockIdx.x;

    __shared__ __align__(16) _Float16 xb [4][2][256];   // [slot][row]
    __shared__ __align__(16) _Float16 h0b[4][2][32];
    __shared__ __align__(16) _Float16 h1b[4][2][64];
    __shared__ __align__(16) _Float16 h2b[4][2][64];
    __shared__ __align__(16) _Float16 gxb[4][2][192];
    __shared__ __align__(16) _Float16 h3s[2][64];
    __shared__ __align__(16) _Float16 rh3s[2][64];
    __shared__ int prog[12];
    __shared__ float sHf[2][64];
    __shared__ float sT[2][64];
    __shared__ float sP[2][12];

    float st0 = 0.f;   // GR h3 state (read in epilogue)

    // zero-init recurrent buffers (all threads, before the per-branch barrier)
    for (int i = tid; i < 4 * 2 * 32;  i += 768) ((_Float16*)h0b)[i] = (_Float16)0.f;
    for (int i = tid; i < 4 * 2 * 64;  i += 768) ((_Float16*)h1b)[i] = (_Float16)0.f;
    for (int i = tid; i < 4 * 2 * 64;  i += 768) ((_Float16*)h2b)[i] = (_Float16)0.f;
    for (int i = tid; i < 4 * 2 * 192; i += 768) ((_Float16*)gxb)[i] = (_Float16)0.f;
    for (int i = tid; i < 2 * 64; i += 768) { ((_Float16*)h3s)[i] = (_Float16)0.f; ((_Float16*)rh3s)[i] = (_Float16)0.f; }
    if (tid < 12) prog[tid] = 0;

    if (wv < 4) {
        // ---------------- lstm2, unit block w: 1 col/lane, quad-gate ----------------
        const int w = wv;
        const int gate = lane >> 4, uo = lane & 15;
        const int col = gate * 64 + 16 * w + uo;
        uint32_t wreg[64];
#pragma unroll
        for (int j = 0; j < 64; ++j)
            wreg[j] = packh(w2g[(2 * j) * 256 + col], w2g[(2 * j + 1) * 256 + col]);
        const float bz = b2g[col];
        __syncthreads();
        float cs0 = 0.f, cs1 = 0.f;
        int cl1[4] = {0, 0, 0, 0}, csb[3] = {0, 0, 0}, cgx = 0;
        for (int t = 0; t < Tsz; ++t) {
#pragma unroll
            for (int s = 0; s < 4; ++s) WAITGE(cl1[s], R_L1U(s), t + 1);   // h1(t)
#pragma unroll
            for (int s = 1; s < 4; ++s) WAITGE(csb[s - 1], R_L2U((w + s) & 3), t); // h2(t-1)
            WAITGE(cgx, R_GX, t - 3);                                      // h2(t-4) freed
#pragma unroll
            for (int r = 0; r < 2; ++r) {
                const uint4* aq = (const uint4*)h1b[t & 3][r];        // k 0..63
                const uint4* bq = (const uint4*)h2b[(t - 1) & 3][r];  // k 64..127
                float a0 = bz, x0 = 0.f;
#pragma unroll
                for (int q = 0; q < 8; ++q) { uint4 v = aq[q]; D4X(a0, x0, &wreg[4 * q], v); }
#pragma unroll
                for (int q = 0; q < 8; ++q) { uint4 v = bq[q]; D4X(a0, x0, &wreg[32 + 4 * q], v); }
                float acc = a0 + x0;
                float tv;
                if (gate == 0)      tv = fsig(acc);
                else if (gate == 1) tv = ftanh(acc);
                else if (gate == 2) tv = fsig(acc + 1.f);
                else                tv = fsig(acc);
                float x16   = __shfl_xor(tv, 16);
                float prod  = tv * x16;
                float prodx = __shfl_xor(prod, 32);
                float cprev = r ? cs1 : cs0;
                float cnew  = tv * cprev + prodx;
                if (gate == 2) { if (r) cs1 = cnew; else cs0 = cnew; }
                float tc  = ftanh(cnew);
                float tcx = __shfl_xor(tc, 16);
                if (gate == 3)
                    h2b[t & 3][r][16 * w + uo] = (_Float16)(tv * tcx);
            }
            SIGNAL(R_L2U(w), t + 1);
        }
    } else if (wv < 8) {
        // ---------------- lstm1, unit block w ----------------
        const int w = wv - 4;
        const int gate = lane >> 4, uo = lane & 15;
        const int col = gate * 64 + 16 * w + uo;
        uint32_t wreg[48];
#pragma unroll
        for (int j = 0; j < 48; ++j)
            wreg[j] = packh(w1g[(2 * j) * 256 + col], w1g[(2 * j + 1) * 256 + col]);
        const float bz = b1g[col];
        __syncthreads();
        float cs0 = 0.f, cs1 = 0.f;
        int cv = 0, csb[3] = {0, 0, 0}, cl2[4] = {0, 0, 0, 0};
        for (int t = 0; t < Tsz; ++t) {
            WAITGE(cv, R_VAN, t + 1);                                      // h0(t)
#pragma unroll
            for (int s = 1; s < 4; ++s) WAITGE(csb[s - 1], R_L1U((w + s) & 3), t); // h1(t-1)
#pragma unroll
            for (int s = 0; s < 4; ++s) WAITGE(cl2[s], R_L2U(s), t - 3);   // h1(t-4) freed
#pragma unroll
            for (int r = 0; r < 2; ++r) {
                const uint4* aq = (const uint4*)h0b[t & 3][r];        // k 0..31
                const uint4* bq = (const uint4*)h1b[(t - 1) & 3][r];  // k 32..95
                float a0 = bz, x0 = 0.f;
#pragma unroll
                for (int q = 0; q < 4; ++q) { uint4 v = aq[q]; D4X(a0, x0, &wreg[4 * q], v); }
#pragma unroll
                for (int q = 0; q < 8; ++q) { uint4 v = bq[q]; D4X(a0, x0, &wreg[16 + 4 * q], v); }
                float acc = a0 + x0;
                float tv;
                if (gate == 0)      tv = fsig(acc);
                else if (gate == 1) tv = ftanh(acc);
                else if (gate == 2) tv = fsig(acc + 1.f);
                else                tv = fsig(acc);
                float x16   = __shfl_xor(tv, 16);
                float prod  = tv * x16;
                float prodx = __shfl_xor(prod, 32);
                float cprev = r ? cs1 : cs0;
                float cnew  = tv * cprev + prodx;
                if (gate == 2) { if (r) cs1 = cnew; else cs0 = cnew; }
                float tc  = ftanh(cnew);
                float tcx = __shfl_xor(tc, 16);
                if (gate == 3)
                    h1b[t & 3][r][16 * w + uo] = (_Float16)(tv * tcx);
            }
            SIGNAL(R_L1U(w), t + 1);
        }
    } else if (wv < 10) {
        // ---------------- gru recurrent, one row ----------------
        const int r = wv - 8;
        uint32_t wreg[96];   // z(0..31) r(32..63) a(64..95)
#pragma unroll
        for (int j = 0; j < 32; ++j) {
            wreg[j]      = packh(gwh[(2 * j) * 192 + lane],       gwh[(2 * j + 1) * 192 + lane]);
            wreg[32 + j] = packh(gwh[(2 * j) * 192 + 64 + lane],  gwh[(2 * j + 1) * 192 + 64 + lane]);
            wreg[64 + j] = packh(gwh[(2 * j) * 192 + 128 + lane], gwh[(2 * j + 1) * 192 + 128 + lane]);
        }
        __syncthreads();
        int cg = 0;
        for (int t = 0; t < Tsz; ++t) {
            WAITGE(cg, R_GX, t + 1);           // gx(t) ready
            const uint4* hq = (const uint4*)h3s[r];
            float az = (float)gxb[t & 3][r][lane];
            float ar = (float)gxb[t & 3][r][64 + lane];
#pragma unroll
            for (int q = 0; q < 8; ++q) {
                uint4 v = hq[q];
                D4(az, &wreg[4 * q], v);
                D4(ar, &wreg[32 + 4 * q], v);
            }
            float z = fsig(az);
            rh3s[r][lane] = (_Float16)(fsig(ar) * st0);
            float ga = (float)gxb[t & 3][r][128 + lane];
            asm volatile("s_waitcnt lgkmcnt(0)" ::: "memory");   // wave-sync LDS
            const uint4* rq = (const uint4*)rh3s[r];
            float aa = ga, ab = 0.f;
#pragma unroll
            for (int q = 0; q < 8; ++q) {
                uint4 v = rq[q];
                if (q & 1) { D4(ab, &wreg[64 + 4 * q], v); }
                else       { D4(aa, &wreg[64 + 4 * q], v); }
            }
            float av = ftanh(aa + ab);
            st0 = (1.f - z) * st0 + z * av;
            h3s[r][lane] = (_Float16)st0;
            SIGNAL(R_GR0 + r, t + 1);
        }
    } else if (wv == 10) {
        // ---------------- van: both rows + pixel staging ----------------
        const int c = lane & 31, s = lane >> 5;
        uint32_t wreg[72];
#pragma unroll
        for (int j = 0; j < 64; ++j)
            wreg[j] = packh(van_wi[(128 * s + 2 * j) * 32 + c],
                            van_wi[(128 * s + 2 * j + 1) * 32 + c]);
#pragma unroll
        for (int j = 0; j < 8; ++j)
            wreg[64 + j] = packh(van_wh[(16 * s + 2 * j) * 32 + c],
                                 van_wh[(16 * s + 2 * j + 1) * 32 + c]);
        const float bz = van_bi[c] + van_bh[c];
        const float* pr0 = pix + (size_t)r0 * Tsz * Dsz;
        const float* pr1 = pr0 + (size_t)Tsz * Dsz;
        float4 pxA0, pxA1, pxB0, pxB1;
#pragma unroll
        for (int t = 0; t < 2; ++t) {
            float4 p0 = *(const float4*)(pr0 + (size_t)t * Dsz + 4 * lane);
            float4 p1 = *(const float4*)(pr1 + (size_t)t * Dsz + 4 * lane);
            uint32_t* x0 = (uint32_t*)xb[t][0];
            uint32_t* x1 = (uint32_t*)xb[t][1];
            x0[2 * lane] = packh(p0.x, p0.y); x0[2 * lane + 1] = packh(p0.z, p0.w);
            x1[2 * lane] = packh(p1.x, p1.y); x1[2 * lane + 1] = packh(p1.z, p1.w);
        }
        pxA0 = *(const float4*)(pr0 + 2 * (size_t)Dsz + 4 * lane);
        pxA1 = *(const float4*)(pr1 + 2 * (size_t)Dsz + 4 * lane);
        pxB0 = *(const float4*)(pr0 + 3 * (size_t)Dsz + 4 * lane);
        pxB1 = *(const float4*)(pr1 + 3 * (size_t)Dsz + 4 * lane);
        __syncthreads();
        int cl[4] = {0, 0, 0, 0};
        for (int t = 0; t < Tsz; ++t) {
#pragma unroll
            for (int ss = 0; ss < 4; ++ss) WAITGE(cl[ss], R_L1U(ss), t - 3);  // h0(t-4) freed
            if (t + 2 < Tsz) {
                uint32_t* x0 = (uint32_t*)xb[(t + 2) & 3][0];
                uint32_t* x1 = (uint32_t*)xb[(t + 2) & 3][1];
                x0[2 * lane] = packh(pxA0.x, pxA0.y); x0[2 * lane + 1] = packh(pxA0.z, pxA0.w);
                x1[2 * lane] = packh(pxA1.x, pxA1.y); x1[2 * lane + 1] = packh(pxA1.z, pxA1.w);
            }
            pxA0 = pxB0; pxA1 = pxB1;
            if (t + 4 < Tsz) {
                pxB0 = *(const float4*)(pr0 + (size_t)(t + 4) * Dsz + 4 * lane);
                pxB1 = *(const float4*)(pr1 + (size_t)(t + 4) * Dsz + 4 * lane);
            }
#pragma unroll
            for (int r = 0; r < 2; ++r) {
                const uint4* xq = ((const uint4*)xb[t & 3][r]) + 16 * s;
                const uint4* hq = ((const uint4*)h0b[(t - 1) & 3][r]) + 2 * s;
                float a0 = 0.f, a1 = 0.f;
#pragma unroll
                for (int q = 0; q < 16; q += 2) {
                    uint4 v0 = xq[q], v1 = xq[q + 1];
                    D4(a0, &wreg[4 * q], v0);
                    D4(a1, &wreg[4 * q + 4], v1);
                }
                {
                    uint4 v0 = hq[0], v1 = hq[1];
                    D4(a0, &wreg[64], v0);
                    D4(a1, &wreg[68], v1);
                }
                float acc = a0 + a1;
                acc += __shfl_xor(acc, 32);
                if (s == 0) h0b[t & 3][r][c] = (_Float16)fmaxf(acc + bz, 0.f);
            }
            SIGNAL(R_VAN, t + 1);
        }
    } else {
        // ---------------- gru gx: both rows, 3 cols/lane ----------------
        uint32_t wreg[96];
#pragma unroll
        for (int j = 0; j < 32; ++j) {
            wreg[j]      = packh(gwi[(2 * j) * 192 + lane],       gwi[(2 * j + 1) * 192 + lane]);
            wreg[32 + j] = packh(gwi[(2 * j) * 192 + 64 + lane],  gwi[(2 * j + 1) * 192 + 64 + lane]);
            wreg[64 + j] = packh(gwi[(2 * j) * 192 + 128 + lane], gwi[(2 * j + 1) * 192 + 128 + lane]);
        }
        const float bz0 = gb[lane], bz1 = gb[64 + lane], bz2 = gb[128 + lane];
        __syncthreads();
        int cl2[4] = {0, 0, 0, 0}, cg0 = 0, cg1 = 0;
        for (int t = 0; t < Tsz; ++t) {
#pragma unroll
            for (int s = 0; s < 4; ++s) WAITGE(cl2[s], R_L2U(s), t + 1);   // h2(t)
            WAITGE(cg0, R_GR0, t - 3);
            WAITGE(cg1, R_GR1, t - 3);
#pragma unroll
            for (int r = 0; r < 2; ++r) {
                const uint4* hq = (const uint4*)h2b[t & 3][r];
                float az = bz0, ar = bz1, aa = bz2;
#pragma unroll
                for (int q = 0; q < 8; ++q) {
                    uint4 v = hq[q];
                    D4(az, &wreg[4 * q], v);
                    D4(ar, &wreg[32 + 4 * q], v);
                    D4(aa, &wreg[64 + 4 * q], v);
                }
                gxb[t & 3][r][lane]       = (_Float16)az;
                gxb[t & 3][r][64 + lane]  = (_Float16)ar;
                gxb[t & 3][r][128 + lane] = (_Float16)aa;
            }
            SIGNAL(R_GX, t + 1);
        }
    }

    if (wv == 8) sHf[0][lane] = st0;
    if (wv == 9) sHf[1][lane] = st0;
    __syncthreads();

    // ---------------- MLP head (2 rows) ----------------
    if (tid < 64) {
        const int r = tid >> 5, c = tid & 31;
        float acc = mb1[c];
#pragma unroll
        for (int kk = 0; kk < 64; ++kk) acc = fmaf(sHf[r][kk], mw1[kk * 32 + c], acc);
        sT[r][c] = fmaxf(acc, 0.f);
    }
    __syncthreads();
    if (tid < 64) {
        const int r = tid >> 5, c = tid & 31;
        float acc = mb2[c];
#pragma unroll
        for (int kk = 0; kk < 32; ++kk) acc = fmaf(sT[r][kk], mw2[kk * 32 + c], acc);
        sT[r][32 + c] = fmaxf(acc, 0.f);
    }
    __syncthreads();
    if (tid < 24) {
        const int r = tid / 12, c = tid - 12 * r;
        float acc = mb3[c];
#pragma unroll
        for (int kk = 0; kk < 32; ++kk) acc = fmaf(sT[r][32 + kk], mw3[kk * 12 + c], acc);
        sP[r][c] = acc;
    }
    __syncthreads();
    if (tid < 2) {
        float acc = 0.f;
#pragma unroll
        for (int kk = 0; kk < 12; ++kk) acc = fmaf(sP[tid][kk], sf[kk], acc);
        out[24 + r0 + tid] = acc;
    }
    if (blockIdx.x == 0 && tid < 12) {
        out[tid] = sf[tid];
        out[12 + tid] = 1.0f;
    }
}

extern "C" void kernel_launch(void* const* d_in, const int* in_sizes, int n_in,
                              void* d_out, int out_size, void* d_ws, size_t ws_size,
                              hipStream_t stream) {
    (void)in_sizes; (void)n_in; (void)d_ws; (void)ws_size; (void)out_size;
    const float* pix    = (const float*)d_in[0];
    const float* van_wi = (const float*)d_in[1];
    const float* van_bi = (const float*)d_in[2];
    const float* van_wh = (const float*)d_in[3];
    const float* van_bh = (const float*)d_in[4];
    const float* w1     = (const float*)d_in[5];
    const float* b1     = (const float*)d_in[6];
    const float* w2     = (const float*)d_in[7];
    const float* b2     = (const float*)d_in[8];
    const float* gwi    = (const float*)d_in[9];
    const float* gwh    = (const float*)d_in[10];
    const float* gb     = (const float*)d_in[11];
    const float* mw1    = (const float*)d_in[12];
    const float* mb1    = (const float*)d_in[13];
    const float* mw2    = (const float*)d_in[14];
    const float* mb2    = (const float*)d_in[15];
    const float* mw3    = (const float*)d_in[16];
    const float* mb3    = (const float*)d_in[17];
    const float* sf     = (const float*)d_in[18];
    float* out = (float*)d_out;

    rnn12e<<<256, 768, 0, stream>>>(
        pix, van_wi, van_bi, van_wh, van_bh,
        w1, b1, w2, b2, gwi, gwh, gb,
        mw1, mb1, mw2, mb2, mw3, mb3, sf, out);
}

// Round 15
// 653.912 us; speedup vs baseline: 1.5499x; 1.5499x over previous
//
#include <hip/hip_runtime.h>
#include <stdint.h>

#define Tsz 512
#define Dsz 256

// role ids (prog[] index)
#define R_VAN 0
#define R_L1A 1
#define R_L1B 2
#define R_L2A 3
#define R_L2B 4
#define R_GX  5
#define R_GR0 6
#define R_GR1 7

union UHp { uint32_t u; _Float16 s[2]; };
__device__ __forceinline__ uint32_t packh(float a, float b) {
    UHp x; x.s[0] = (_Float16)a; x.s[1] = (_Float16)b; return x.u;
}
__device__ __forceinline__ float dot2(uint32_t w, uint32_t a, float c) {
#if __has_builtin(__builtin_amdgcn_fdot2)
    typedef _Float16 h2 __attribute__((ext_vector_type(2)));
    union U { uint32_t u; h2 h; };
    U W, A; W.u = w; A.u = a;
    return __builtin_amdgcn_fdot2(W.h, A.h, c, false);
#else
    float d;
    asm("v_dot2_f32_f16 %0, %1, %2, %3" : "=v"(d) : "v"(w), "v"(a), "v"(c));
    return d;
#endif
}

// ---- cheap transcendentals: v_exp_f32 + v_rcp_f32 (no IEEE div sequence) ----
// Default fsig/ftanh compiled to ~9-inst div_scale/div_fmas/div_fixup chains,
// executed on BOTH sides of the divergent gate branches -> ~100+ VALU
// insts/wave/ts of nonlinearity. rcp is ~1 ulp; threshold margin is 18x.
__device__ __forceinline__ float fexp2(float x) {
#if __has_builtin(__builtin_amdgcn_exp2f)
    return __builtin_amdgcn_exp2f(x);
#else
    return exp2f(x);
#endif
}
__device__ __forceinline__ float frcp(float x) {
#if __has_builtin(__builtin_amdgcn_rcpf)
    return __builtin_amdgcn_rcpf(x);
#else
    return 1.0f / x;
#endif
}
#define LOG2E 1.44269504f
__device__ __forceinline__ float fsig(float x)  { return frcp(1.0f + fexp2(-LOG2E * x)); }
__device__ __forceinline__ float ftanh(float x) { return 2.0f * frcp(1.0f + fexp2(-2.0f * LOG2E * x)) - 1.0f; }

#define D4(ACC, WP, V) \
    do { ACC = dot2((WP)[0], (V).x, ACC); ACC = dot2((WP)[1], (V).y, ACC); \
         ACC = dot2((WP)[2], (V).z, ACC); ACC = dot2((WP)[3], (V).w, ACC); } while (0)
#define D4X(A, X, WP, V) \
    do { A = dot2((WP)[0], (V).x, A); X = dot2((WP)[1], (V).y, X); \
         A = dot2((WP)[2], (V).z, A); X = dot2((WP)[3], (V).w, X); } while (0)

// cached flag wait (monotonic counters; re-read only when cache insufficient)
#define WAITGE(cache, ridx, need) \
    do { if ((cache) < (need)) { \
        volatile const int* _pf = (volatile const int*)&prog[(ridx)]; \
        int _v = *_pf; \
        while (_v < (need)) _v = *_pf; \
        (cache) = _v; } } while (0)

#define SIGNAL(ridx, val) \
    do { asm volatile("s_waitcnt lgkmcnt(0)" ::: "memory"); \
         *((volatile int*)&prog[(ridx)]) = (val); } while (0)

// r13 champion structure (8 waves, elastic flag pipeline, 2 rows/block, grid
// 256, waves_per_eu(2,2)). ONLY the nonlinearity changed:
//  (a) fsig/ftanh use v_rcp (above);
//  (b) L1/L2 gate math is BRANCHLESS: every lane computes two sigmoids with
//      lane-selected inputs (tanh(g) = 2*sig(2g)-1), combine via shfl, store
//      predicated on odd. No dual-path exec-masked transcendentals.
//      Even lanes' cs registers hold bounded garbage (|prx|<1, sig<1 -> no
//      NaN; rcp(inf)=0 keeps ftanh finite); they are never stored.
__global__ __attribute__((amdgpu_flat_work_group_size(512, 512),
                          amdgpu_waves_per_eu(2, 2)))
void rnn_flag2(
    const float* __restrict__ pix,
    const float* __restrict__ van_wi, const float* __restrict__ van_bi,
    const float* __restrict__ van_wh, const float* __restrict__ van_bh,
    const float* __restrict__ w1g, const float* __restrict__ b1g,
    const float* __restrict__ w2g, const float* __restrict__ b2g,
    const float* __restrict__ gwi, const float* __restrict__ gwh,
    const float* __restrict__ gb,
    const float* __restrict__ mw1, const float* __restrict__ mb1,
    const float* __restrict__ mw2, const float* __restrict__ mb2,
    const float* __restrict__ mw3, const float* __restrict__ mb3,
    const float* __restrict__ sf,
    float* __restrict__ out)
{
    const int tid  = threadIdx.x;
    const int wv   = tid >> 6;
    const int lane = tid & 63;
    const int r0   = 2 * blockIdx.x;

    int role;
    switch (wv) {
        case 0: role = R_L2A; break;
        case 1: role = R_L2B; break;
        case 2: role = R_VAN; break;
        case 3: role = R_GX;  break;
        case 4: role = R_GR0; break;
        case 5: role = R_GR1; break;
        case 6: role = R_L1A; break;
        default: role = R_L1B; break;
    }

    __shared__ __align__(16) _Float16 xb [4][2][256];   // [slot][row]
    __shared__ __align__(16) _Float16 h0b[4][2][32];
    __shared__ __align__(16) _Float16 h1b[4][2][64];
    __shared__ __align__(16) _Float16 h2b[4][2][64];
    __shared__ __align__(16) _Float16 gxb[4][2][192];
    __shared__ __align__(16) _Float16 h3s[2][64];       // gru-wave private per row
    __shared__ __align__(16) _Float16 rh3s[2][64];
    __shared__ int prog[8];
    __shared__ float sHf[2][64];
    __shared__ float sT[2][64];
    __shared__ float sP[2][12];

    uint32_t wreg[128];
    float bz0 = 0.f, bz1 = 0.f, bz2 = 0.f;
    float st0 = 0.f, st1 = 0.f;          // lstm c (rows 0/1) or gru h3 (own row)
    float4 pxA0{}, pxB0{}, pxA1{}, pxB1{};
    const float* pr0 = nullptr; const float* pr1 = nullptr;

    // ---------------- per-role weight load (once) ----------------
    if (role == R_VAN) {
        const int c = lane & 31, s = lane >> 5;
#pragma unroll
        for (int j = 0; j < 64; ++j)
            wreg[j] = packh(van_wi[(128 * s + 2 * j) * 32 + c],
                            van_wi[(128 * s + 2 * j + 1) * 32 + c]);
#pragma unroll
        for (int j = 0; j < 8; ++j)
            wreg[64 + j] = packh(van_wh[(16 * s + 2 * j) * 32 + c],
                                 van_wh[(16 * s + 2 * j + 1) * 32 + c]);
        bz0 = van_bi[c] + van_bh[c];
        pr0 = pix + (size_t)r0 * Tsz * Dsz;
        pr1 = pr0 + (size_t)Tsz * Dsz;
        // prologue: x(0),x(1) -> slots 0,1; pxA=x(2), pxB=x(3)
#pragma unroll
        for (int t = 0; t < 2; ++t) {
            float4 p0 = *(const float4*)(pr0 + (size_t)t * Dsz + 4 * lane);
            float4 p1 = *(const float4*)(pr1 + (size_t)t * Dsz + 4 * lane);
            uint32_t* x0 = (uint32_t*)xb[t][0];
            uint32_t* x1 = (uint32_t*)xb[t][1];
            x0[2 * lane] = packh(p0.x, p0.y); x0[2 * lane + 1] = packh(p0.z, p0.w);
            x1[2 * lane] = packh(p1.x, p1.y); x1[2 * lane + 1] = packh(p1.z, p1.w);
        }
        pxA0 = *(const float4*)(pr0 + 2 * (size_t)Dsz + 4 * lane);
        pxA1 = *(const float4*)(pr1 + 2 * (size_t)Dsz + 4 * lane);
        pxB0 = *(const float4*)(pr0 + 3 * (size_t)Dsz + 4 * lane);
        pxB1 = *(const float4*)(pr1 + 3 * (size_t)Dsz + 4 * lane);
    } else if (role == R_L1A || role == R_L1B) {
        const int p = (role == R_L1A ? 0 : 64) + lane;
        const int u = p >> 1, odd = p & 1;
        const int c0 = odd ? 128 + u : u, c1 = c0 + 64;
#pragma unroll
        for (int j = 0; j < 48; ++j)
            wreg[j] = packh(w1g[(2 * j) * 256 + c0], w1g[(2 * j + 1) * 256 + c0]);
#pragma unroll
        for (int j = 0; j < 48; ++j)
            wreg[48 + j] = packh(w1g[(2 * j) * 256 + c1], w1g[(2 * j + 1) * 256 + c1]);
        bz0 = b1g[c0]; bz1 = b1g[c1];
    } else if (role == R_L2A || role == R_L2B) {
        const int p = (role == R_L2A ? 0 : 64) + lane;
        const int u = p >> 1, odd = p & 1;
        const int c0 = odd ? 128 + u : u, c1 = c0 + 64;
#pragma unroll
        for (int j = 0; j < 64; ++j)
            wreg[j] = packh(w2g[(2 * j) * 256 + c0], w2g[(2 * j + 1) * 256 + c0]);
#pragma unroll
        for (int j = 0; j < 64; ++j)
            wreg[64 + j] = packh(w2g[(2 * j) * 256 + c1], w2g[(2 * j + 1) * 256 + c1]);
        bz0 = b2g[c0]; bz1 = b2g[c1];
    } else if (role == R_GX) {
#pragma unroll
        for (int j = 0; j < 32; ++j) {
            wreg[j]      = packh(gwi[(2 * j) * 192 + lane],       gwi[(2 * j + 1) * 192 + lane]);
            wreg[32 + j] = packh(gwi[(2 * j) * 192 + 64 + lane],  gwi[(2 * j + 1) * 192 + 64 + lane]);
            wreg[64 + j] = packh(gwi[(2 * j) * 192 + 128 + lane], gwi[(2 * j + 1) * 192 + 128 + lane]);
        }
        bz0 = gb[lane]; bz1 = gb[64 + lane]; bz2 = gb[128 + lane];
    } else {   // R_GR0 / R_GR1
#pragma unroll
        for (int j = 0; j < 32; ++j) {
            wreg[j]      = packh(gwh[(2 * j) * 192 + lane],       gwh[(2 * j + 1) * 192 + lane]);
            wreg[32 + j] = packh(gwh[(2 * j) * 192 + 64 + lane],  gwh[(2 * j + 1) * 192 + 64 + lane]);
            wreg[64 + j] = packh(gwh[(2 * j) * 192 + 128 + lane], gwh[(2 * j + 1) * 192 + 128 + lane]);
        }
    }

    for (int i = tid; i < 4 * 2 * 32;  i += 512) ((_Float16*)h0b)[i] = (_Float16)0.f;
    for (int i = tid; i < 4 * 2 * 64;  i += 512) ((_Float16*)h1b)[i] = (_Float16)0.f;
    for (int i = tid; i < 4 * 2 * 64;  i += 512) ((_Float16*)h2b)[i] = (_Float16)0.f;
    for (int i = tid; i < 4 * 2 * 192; i += 512) ((_Float16*)gxb)[i] = (_Float16)0.f;
    for (int i = tid; i < 2 * 64; i += 512) { ((_Float16*)h3s)[i] = (_Float16)0.f; ((_Float16*)rh3s)[i] = (_Float16)0.f; }
    if (tid < 8) prog[tid] = 0;
    __syncthreads();

    // ---------------- elastic pipelined recurrence (no barriers) ----------------
    if (role == R_VAN) {
        const int c = lane & 31, s = lane >> 5;
        int cA = 0, cB = 0;
        for (int t = 0; t < Tsz; ++t) {
            WAITGE(cA, R_L1A, t - 3);
            WAITGE(cB, R_L1B, t - 3);
            if (t + 2 < Tsz) {
                uint32_t* x0 = (uint32_t*)xb[(t + 2) & 3][0];
                uint32_t* x1 = (uint32_t*)xb[(t + 2) & 3][1];
                x0[2 * lane] = packh(pxA0.x, pxA0.y); x0[2 * lane + 1] = packh(pxA0.z, pxA0.w);
                x1[2 * lane] = packh(pxA1.x, pxA1.y); x1[2 * lane + 1] = packh(pxA1.z, pxA1.w);
            }
            pxA0 = pxB0; pxA1 = pxB1;
            if (t + 4 < Tsz) {
                pxB0 = *(const float4*)(pr0 + (size_t)(t + 4) * Dsz + 4 * lane);
                pxB1 = *(const float4*)(pr1 + (size_t)(t + 4) * Dsz + 4 * lane);
            }
#pragma unroll
            for (int r = 0; r < 2; ++r) {
                const uint4* xq = ((const uint4*)xb[t & 3][r]) + 16 * s;
                const uint4* hq = ((const uint4*)h0b[(t - 1) & 3][r]) + 2 * s;
                float a0 = 0.f, a1 = 0.f;
#pragma unroll
                for (int q = 0; q < 16; q += 2) {
                    uint4 v0 = xq[q], v1 = xq[q + 1];
                    D4(a0, &wreg[4 * q], v0);
                    D4(a1, &wreg[4 * q + 4], v1);
                }
                {
                    uint4 v0 = hq[0], v1 = hq[1];
                    D4(a0, &wreg[64], v0);
                    D4(a1, &wreg[68], v1);
                }
                float acc = a0 + a1;
                acc += __shfl_xor(acc, 32);
                if (s == 0) h0b[t & 3][r][c] = (_Float16)fmaxf(acc + bz0, 0.f);
            }
            SIGNAL(R_VAN, t + 1);
        }
    } else if (role == R_L1A || role == R_L1B) {
        const int prt = (role == R_L1A) ? R_L1B : R_L1A;
        const int p = (role == R_L1A ? 0 : 64) + lane;
        const int u = p >> 1, odd = p & 1;
        int cv = 0, cp = 0, c2a = 0, c2b = 0;
        for (int t = 0; t < Tsz; ++t) {
            WAITGE(cv, R_VAN, t + 1);          // h0(t) ready
            WAITGE(cp, prt, t);                // partner's h1(t-1) half ready
            WAITGE(c2a, R_L2A, t - 3);         // h1(t-4) consumed before overwrite
            WAITGE(c2b, R_L2B, t - 3);
#pragma unroll
            for (int r = 0; r < 2; ++r) {
                const uint4* aq = (const uint4*)h0b[t & 3][r];        // k 0..31
                const uint4* bq = (const uint4*)h1b[(t - 1) & 3][r];  // k 32..95
                float a0 = bz0, a1 = bz1, x0 = 0.f, x1 = 0.f;
#pragma unroll
                for (int q = 0; q < 4; ++q) {
                    uint4 v = aq[q];
                    D4X(a0, x0, &wreg[4 * q], v);
                    D4X(a1, x1, &wreg[48 + 4 * q], v);
                }
#pragma unroll
                for (int q = 0; q < 8; ++q) {
                    uint4 v = bq[q];
                    D4X(a0, x0, &wreg[16 + 4 * q], v);
                    D4X(a1, x1, &wreg[64 + 4 * q], v);
                }
                float g0 = a0 + x0, g1 = a1 + x1;
                // branchless gates: even lane holds (i,g) cols, odd (f,o)
                float ain = odd ? g0 + 1.f : g0;       // sig arg: f+1 | i
                float bin = odd ? g1 : g1 + g1;        // sig arg: o | 2g
                float s0 = fsig(ain);
                float s1 = fsig(bin);
                float send = s0 * (2.f * s1 - 1.f);    // even: sig(i)*tanh(g)
                float prx = __shfl_xor(send, 1);
                float cs = r ? st1 : st0;
                cs = s0 * cs + prx;                    // odd: sig(f+1)*c + i*g
                if (r) st1 = cs; else st0 = cs;
                float tc = ftanh(cs);
                if (odd) h1b[t & 3][r][u] = (_Float16)(s1 * tc);
            }
            SIGNAL(role, t + 1);
        }
    } else if (role == R_L2A || role == R_L2B) {
        const int prt = (role == R_L2A) ? R_L2B : R_L2A;
        const int p = (role == R_L2A ? 0 : 64) + lane;
        const int u = p >> 1, odd = p & 1;
        int c1a = 0, c1b = 0, cp = 0, cg = 0;
        for (int t = 0; t < Tsz; ++t) {
            WAITGE(c1a, R_L1A, t + 1);         // h1(t) ready (both halves)
            WAITGE(c1b, R_L1B, t + 1);
            WAITGE(cp, prt, t);                // partner's h2(t-1) half
            WAITGE(cg, R_GX, t - 3);           // h2(t-4) consumed before overwrite
#pragma unroll
            for (int r = 0; r < 2; ++r) {
                const uint4* aq = (const uint4*)h1b[t & 3][r];        // k 0..63
                const uint4* bq = (const uint4*)h2b[(t - 1) & 3][r];  // k 64..127
                float a0 = bz0, a1 = bz1, x0 = 0.f, x1 = 0.f;
#pragma unroll
                for (int q = 0; q < 8; ++q) {
                    uint4 v = aq[q];
                    D4X(a0, x0, &wreg[4 * q], v);
                    D4X(a1, x1, &wreg[64 + 4 * q], v);
                }
#pragma unroll
                for (int q = 0; q < 8; ++q) {
                    uint4 v = bq[q];
                    D4X(a0, x0, &wreg[32 + 4 * q], v);
                    D4X(a1, x1, &wreg[96 + 4 * q], v);
                }
                float g0 = a0 + x0, g1 = a1 + x1;
                float ain = odd ? g0 + 1.f : g0;
                float bin = odd ? g1 : g1 + g1;
                float s0 = fsig(ain);
                float s1 = fsig(bin);
                float send = s0 * (2.f * s1 - 1.f);
                float prx = __shfl_xor(send, 1);
                float cs = r ? st1 : st0;
                cs = s0 * cs + prx;
                if (r) st1 = cs; else st0 = cs;
                float tc = ftanh(cs);
                if (odd) h2b[t & 3][r][u] = (_Float16)(s1 * tc);
            }
            SIGNAL(role, t + 1);
        }
    } else if (role == R_GX) {
        int c2a = 0, c2b = 0, g0c = 0, g1c = 0;
        for (int t = 0; t < Tsz; ++t) {
            WAITGE(c2a, R_L2A, t + 1);         // h2(t) ready
            WAITGE(c2b, R_L2B, t + 1);
            WAITGE(g0c, R_GR0, t - 3);         // gxb(t-4) consumed before overwrite
            WAITGE(g1c, R_GR1, t - 3);
#pragma unroll
            for (int r = 0; r < 2; ++r) {
                const uint4* hq = (const uint4*)h2b[t & 3][r];
                float az = bz0, ar = bz1, aa = bz2;
#pragma unroll
                for (int q = 0; q < 8; ++q) {
                    uint4 v = hq[q];
                    D4(az, &wreg[4 * q], v);
                    D4(ar, &wreg[32 + 4 * q], v);
                    D4(aa, &wreg[64 + 4 * q], v);
                }
                gxb[t & 3][r][lane]       = (_Float16)az;
                gxb[t & 3][r][64 + lane]  = (_Float16)ar;
                gxb[t & 3][r][128 + lane] = (_Float16)aa;
            }
            SIGNAL(R_GX, t + 1);
        }
    } else {   // R_GR0 / R_GR1
        const int r = (role == R_GR0) ? 0 : 1;
        int cg = 0;
        for (int t = 0; t < Tsz; ++t) {
            WAITGE(cg, R_GX, t + 1);           // gx(t) ready
            const uint4* hq = (const uint4*)h3s[r];
            float az = (float)gxb[t & 3][r][lane];
            float ar = (float)gxb[t & 3][r][64 + lane];
#pragma unroll
            for (int q = 0; q < 8; ++q) {
                uint4 v = hq[q];
                D4(az, &wreg[4 * q], v);
                D4(ar, &wreg[32 + 4 * q], v);
            }
            float z = fsig(az);
            rh3s[r][lane] = (_Float16)(fsig(ar) * st0);
            float ga = (float)gxb[t & 3][r][128 + lane];
            asm volatile("s_waitcnt lgkmcnt(0)" ::: "memory");   // wave-sync LDS
            const uint4* rq = (const uint4*)rh3s[r];
            float aa = ga, ab = 0.f;
#pragma unroll
            for (int q = 0; q < 8; ++q) {
                uint4 v = rq[q];
                if (q & 1) { D4(ab, &wreg[64 + 4 * q], v); }
                else       { D4(aa, &wreg[64 + 4 * q], v); }
            }
            float av = ftanh(aa + ab);
            st0 = (1.f - z) * st0 + z * av;
            h3s[r][lane] = (_Float16)st0;
            SIGNAL(role, t + 1);
        }
    }

    if (role == R_GR0) sHf[0][lane] = st0;
    if (role == R_GR1) sHf[1][lane] = st0;
    __syncthreads();

    // ---------------- MLP head (2 rows) ----------------
    if (tid < 64) {
        const int r = tid >> 5, c = tid & 31;
        float acc = mb1[c];
#pragma unroll
        for (int kk = 0; kk < 64; ++kk) acc = fmaf(sHf[r][kk], mw1[kk * 32 + c], acc);
        sT[r][c] = fmaxf(acc, 0.f);
    }
    __syncthreads();
    if (tid < 64) {
        const int r = tid >> 5, c = tid & 31;
        float acc = mb2[c];
#pragma unroll
        for (int kk = 0; kk < 32; ++kk) acc = fmaf(sT[r][kk], mw2[kk * 32 + c], acc);
        sT[r][32 + c] = fmaxf(acc, 0.f);
    }
    __syncthreads();
    if (tid < 24) {
        const int r = tid / 12, c = tid - 12 * r;
        float acc = mb3[c];
#pragma unroll
        for (int kk = 0; kk < 32; ++kk) acc = fmaf(sT[r][32 + kk], mw3[kk * 12 + c], acc);
        sP[r][c] = acc;
    }
    __syncthreads();
    if (tid < 2) {
        float acc = 0.f;
#pragma unroll
        for (int kk = 0; kk < 12; ++kk) acc = fmaf(sP[tid][kk], sf[kk], acc);
        out[24 + r0 + tid] = acc;
    }
    if (blockIdx.x == 0 && tid < 12) {
        out[tid] = sf[tid];
        out[12 + tid] = 1.0f;
    }
}

extern "C" void kernel_launch(void* const* d_in, const int* in_sizes, int n_in,
                              void* d_out, int out_size, void* d_ws, size_t ws_size,
                              hipStream_t stream) {
    (void)in_sizes; (void)n_in; (void)d_ws; (void)ws_size; (void)out_size;
    const float* pix    = (const float*)d_in[0];
    const float* van_wi = (const float*)d_in[1];
    const float* van_bi = (const float*)d_in[2];
    const float* van_wh = (const float*)d_in[3];
    const float* van_bh = (const float*)d_in[4];
    const float* w1     = (const float*)d_in[5];
    const float* b1     = (const float*)d_in[6];
    const float* w2     = (const float*)d_in[7];
    const float* b2     = (const float*)d_in[8];
    const float* gwi    = (const float*)d_in[9];
    const float* gwh    = (const float*)d_in[10];
    const float* gb     = (const float*)d_in[11];
    const float* mw1    = (const float*)d_in[12];
    const float* mb1    = (const float*)d_in[13];
    const float* mw2    = (const float*)d_in[14];
    const float* mb2    = (const float*)d_in[15];
    const float* mw3    = (const float*)d_in[16];
    const float* mb3    = (const float*)d_in[17];
    const float* sf     = (const float*)d_in[18];
    float* out = (float*)d_out;

    rnn_flag2<<<256, 512, 0, stream>>>(
        pix, van_wi, van_bi, van_wh, van_bh,
        w1, b1, w2, b2, gwi, gwh, gb,
        mw1, mb1, mw2, mb2, mw3, mb3, sf, out);
}